// Round 1
// baseline (448.630 us; speedup 1.0000x reference)
//
#include <hip/hip_runtime.h>
#include <stdint.h>

// Problem: out[b,o,h,w] = sum_c x[b,c,h,w] * Wg[(h%4)*4+(w%4), o, c]
// B=16, Cs=Ct=512, H=W=64. 16 phase-GEMMs: M=512, K=512, N=4096.
// Strategy: fp32 -> bf16 on the fly, mfma_f32_16x16x32_bf16, 128x128 tiles.

typedef __attribute__((ext_vector_type(8))) short short8;
typedef __attribute__((ext_vector_type(4))) float f32x4;

#define CS 512
#define CT 512
#define HW 4096          // 64*64 spatial
#define MT 128
#define NT 128
#define BK 32
#define LDA 40           // BK + 8 pad (bf16 elems) -> 80B rows, 16B aligned

__device__ __forceinline__ uint16_t f32_to_bf16(float f) {
    uint32_t u = __builtin_bit_cast(uint32_t, f);
    u += 0x7FFFu + ((u >> 16) & 1u);      // round-to-nearest-even
    return (uint16_t)(u >> 16);
}

__global__ __launch_bounds__(256)
void gwl_kernel(const float* __restrict__ x, const float* __restrict__ Wg,
                float* __restrict__ out) {
    const int pb = blockIdx.x;   // pixel block 0..31
    const int mb = blockIdx.y;   // out-channel block 0..3
    const int ph = blockIdx.z;   // phase 0..15
    const int r = ph >> 2, q = ph & 3;
    const int n0 = pb * NT;
    const int m0 = mb * MT;

    __shared__ __align__(16) uint16_t As[MT][LDA];  // [m][k] bf16
    __shared__ __align__(16) uint16_t Bs[NT][LDA];  // [n][k] bf16 (k contiguous)

    const int t = threadIdx.x;
    const int lane = t & 63;
    const int wave = t >> 6;

    // ---- A staging: thread owns m_a = t>>1, k-half kh_a = (t&1)*16
    const int m_a = t >> 1;
    const int kh_a = (t & 1) << 4;
    const float* aptr = Wg + (size_t)ph * CT * CS + (size_t)(m0 + m_a) * CS + kh_a;

    // ---- B staging: thread owns pixel n_b = t&127, k-half kh_b = (t>>7)*16
    const int n_b = t & 127;
    const int kh_b = (t >> 7) << 4;
    const int ng = n0 + n_b;                 // global pixel id within phase
    const int bi = ng >> 8;                  // batch
    const int h4 = (ng >> 4) & 15;
    const int w4 = ng & 15;
    const float* bptr = x + (size_t)bi * CS * HW + (size_t)kh_b * HW
                          + (size_t)((h4 * 4 + r) * 64 + (w4 * 4 + q));

    const int qd = lane >> 4;   // quad 0..3
    const int lr = lane & 15;
    const int wm = (wave >> 1) * 64;   // wave M offset in tile
    const int wn = (wave & 1) * 64;    // wave N offset in tile

    f32x4 acc[4][4] = {};

    for (int k0 = 0; k0 < CS; k0 += BK) {
        // global loads first (overlap with previous iteration's MFMA drain)
        float4 av4[4];
        const float4* af4 = (const float4*)(aptr + k0);
        #pragma unroll
        for (int j = 0; j < 4; ++j) av4[j] = af4[j];

        float bv[16];
        const float* bp = bptr + (size_t)k0 * HW;
        #pragma unroll
        for (int j = 0; j < 16; ++j) bv[j] = bp[(size_t)j * HW];

        __syncthreads();   // previous iteration's ds_reads complete

        // convert + LDS write (16B stores)
        __align__(16) uint16_t ab[16];
        __align__(16) uint16_t bb[16];
        const float* av = (const float*)av4;
        #pragma unroll
        for (int j = 0; j < 16; ++j) ab[j] = f32_to_bf16(av[j]);
        #pragma unroll
        for (int j = 0; j < 16; ++j) bb[j] = f32_to_bf16(bv[j]);

        ((short8*)&As[m_a][kh_a])[0] = ((const short8*)ab)[0];
        ((short8*)&As[m_a][kh_a])[1] = ((const short8*)ab)[1];
        ((short8*)&Bs[n_b][kh_b])[0] = ((const short8*)bb)[0];
        ((short8*)&Bs[n_b][kh_b])[1] = ((const short8*)bb)[1];

        __syncthreads();

        // fragment reads: a_frag[j] = A[m = lane&15][k = qd*8 + j]
        short8 afr[4], bfr[4];
        #pragma unroll
        for (int i = 0; i < 4; ++i)
            afr[i] = *(const short8*)&As[wm + i * 16 + lr][qd * 8];
        #pragma unroll
        for (int i = 0; i < 4; ++i)
            bfr[i] = *(const short8*)&Bs[wn + i * 16 + lr][qd * 8];

        #pragma unroll
        for (int i = 0; i < 4; ++i)
            #pragma unroll
            for (int j = 0; j < 4; ++j)
                acc[i][j] = __builtin_amdgcn_mfma_f32_16x16x32_bf16(
                    afr[i], bfr[j], acc[i][j], 0, 0, 0);
    }

    // epilogue: C/D layout col = lane&15 (N), row = qd*4 + reg (M)
    #pragma unroll
    for (int j = 0; j < 4; ++j) {
        const int n = n0 + wn + j * 16 + lr;
        const int obi = n >> 8;
        const int oh4 = (n >> 4) & 15;
        const int ow4 = n & 15;
        float* op = out + (size_t)obi * CT * HW
                        + (size_t)((oh4 * 4 + r) * 64 + (ow4 * 4 + q));
        #pragma unroll
        for (int i = 0; i < 4; ++i) {
            const int m = m0 + wm + i * 16 + qd * 4;
            #pragma unroll
            for (int g = 0; g < 4; ++g)
                op[(size_t)(m + g) * HW] = acc[i][j][g];
        }
    }
}

extern "C" void kernel_launch(void* const* d_in, const int* in_sizes, int n_in,
                              void* d_out, int out_size, void* d_ws, size_t ws_size,
                              hipStream_t stream) {
    const float* x  = (const float*)d_in[0];
    const float* Wg = (const float*)d_in[1];
    float* out = (float*)d_out;
    dim3 grid(4096 / NT, CT / MT, 16);   // 32 x 4 x 16 = 2048 blocks
    gwl_kernel<<<grid, dim3(256), 0, stream>>>(x, Wg, out);
}

// Round 2
// 319.700 us; speedup vs baseline: 1.4033x; 1.4033x over previous
//
#include <hip/hip_runtime.h>
#include <stdint.h>

// out[b,o,h,w] = sum_c x[b,c,h,w] * Wg[(h%4)*4+(w%4), o, c]
// B=16, Cs=Ct=512, H=W=64.
// Round-2: all 4 q-phases (w%4) in one block -> dense float4 B loads and
// full-line stores via LDS-transpose epilogue. A pre-converted to bf16 (d_ws)
// and staged with global_load_lds. Wave w computes phase q=w: M=64 x Nq=64.

typedef __attribute__((ext_vector_type(8))) short short8;
typedef __attribute__((ext_vector_type(4))) float f32x4;

#define CS 512
#define CT 512
#define HW 4096
#define BK 32
#define MT 64       // out-channel rows per block
#define BPITCH 40   // Bs row pitch in uint16 (80B, 16B-multiple)

__device__ __forceinline__ uint16_t f32_to_bf16(float f) {
    uint32_t u = __builtin_bit_cast(uint32_t, f);
    u += 0x7FFFu + ((u >> 16) & 1u);     // RNE
    return (uint16_t)(u >> 16);
}

__global__ __launch_bounds__(256)
void w2_cvt(const float* __restrict__ Wg, uint16_t* __restrict__ W2) {
    int idx = (blockIdx.x * 256 + threadIdx.x) * 8;
    float4 a = *(const float4*)(Wg + idx);
    float4 b = *(const float4*)(Wg + idx + 4);
    uint16_t o[8];
    o[0]=f32_to_bf16(a.x); o[1]=f32_to_bf16(a.y); o[2]=f32_to_bf16(a.z); o[3]=f32_to_bf16(a.w);
    o[4]=f32_to_bf16(b.x); o[5]=f32_to_bf16(b.y); o[6]=f32_to_bf16(b.z); o[7]=f32_to_bf16(b.w);
    *(short8*)(W2 + idx) = *(short8*)o;
}

template<bool USE_W2>
__global__ __launch_bounds__(256, 3)
void gwl_main(const float* __restrict__ x, const float* __restrict__ Wg,
              const uint16_t* __restrict__ W2, float* __restrict__ out) {
    const int nb = blockIdx.x;   // pixel-row block: rows 4*nb..4*nb+3 of (b*16+h4)
    const int mb = blockIdx.y;   // out-channel block (64 rows)
    const int r  = blockIdx.z;   // h%4 phase
    const int m0 = mb * MT;

    // LDS: As [4 q][64 m][32 k] bf16 unpadded (glds layout), 16KB
    //      Bs [4 q][64 n][BPITCH] bf16, 20KB
    //      T  (epilogue, aliased over As/Bs) [16 m][4 rho][68 w] f32, 17408B
    __shared__ __align__(16) unsigned char smem[36864];
    uint16_t* As = (uint16_t*)smem;
    uint16_t* Bs = (uint16_t*)(smem + 16384);
    float*    T  = (float*)smem;

    const int tid  = threadIdx.x;
    const int lane = tid & 63;
    const int wave = tid >> 6;      // compute: q; staging roles below
    const int lr = lane & 15, qd = lane >> 4;

    // ---- B staging coords: thread = (w16 = tid&15, rho = (tid>>4)&3, kw = wave)
    const int w16 = tid & 15;
    const int rho = (tid >> 4) & 3;
    const int kw  = tid >> 6;
    const int rg  = nb * 4 + rho;       // global (b*16 + h4) row
    const int bb  = rg >> 4;
    const int h4  = rg & 15;
    const float* bbase = x + (size_t)bb * CS * HW
                           + (size_t)((h4 * 4 + r) * 64 + w16 * 4);

    // ---- A staging (bf16 via global_load_lds): wave loads its q tile
    const uint16_t* abase = USE_W2
        ? W2 + ((size_t)(r * 4 + wave) * CT + m0) * CS : (const uint16_t*)nullptr;

    float4 breg[8];
    auto loadB = [&](int k0) {
        const float* p = bbase + (size_t)(k0 + kw * 8) * HW;
        #pragma unroll
        for (int cc = 0; cc < 8; ++cc) breg[cc] = *(const float4*)(p + (size_t)cc * HW);
    };
    auto writeB = [&]() {
        #pragma unroll
        for (int q = 0; q < 4; ++q) {
            uint16_t tmp[8];
            #pragma unroll
            for (int cc = 0; cc < 8; ++cc)
                tmp[cc] = f32_to_bf16(((const float*)&breg[cc])[q]);
            *(short8*)(Bs + (q * 64 + rho * 16 + w16) * BPITCH + kw * 8) = *(short8*)tmp;
        }
    };
    auto stageA_glds = [&](int k0) {
        #pragma unroll
        for (int t = 0; t < 4; ++t) {
            const uint16_t* src = abase + (size_t)(t * 16 + (lane >> 2)) * CS
                                        + k0 + (lane & 3) * 8;
            uint16_t* dst = As + wave * 2048 + t * 512;   // + lane*8 elems by HW
            __builtin_amdgcn_global_load_lds(
                (const __attribute__((address_space(1))) void*)src,
                (__attribute__((address_space(3))) void*)dst, 16, 0, 0);
        }
    };
    auto stageA_fp32 = [&](int k0) {
        const int qa = tid >> 6, rem = tid & 63;
        const int ka = rem & 7, ma = rem >> 3;
        const float* ap = Wg + ((size_t)(r * 4 + qa) * CT + m0 + ma) * CS + k0 + ka * 4;
        #pragma unroll
        for (int it = 0; it < 8; ++it) {
            float4 v = *(const float4*)(ap + (size_t)it * 8 * CS);
            uint16_t tmp[4] = {f32_to_bf16(v.x), f32_to_bf16(v.y),
                               f32_to_bf16(v.z), f32_to_bf16(v.w)};
            *(uint64_t*)(As + qa * 2048 + (ma + it * 8) * 32 + ka * 4) =
                *(const uint64_t*)tmp;
        }
    };

    f32x4 acc[4][4] = {};

    // prologue: fill tile 0, prefetch B regs for tile 1
    loadB(0);
    if (USE_W2) stageA_glds(0); else stageA_fp32(0);
    writeB();
    loadB(BK);

    const uint16_t* Asq = As + wave * 2048;
    const uint16_t* Bsq = Bs + wave * 64 * BPITCH;

    for (int k = 0; k < 16; ++k) {
        __syncthreads();                       // tile k fill complete
        short8 afr[4], bfr[4];
        #pragma unroll
        for (int i = 0; i < 4; ++i)
            afr[i] = *(const short8*)(Asq + (i * 16 + lr) * 32 + qd * 8);
        #pragma unroll
        for (int j = 0; j < 4; ++j)
            bfr[j] = *(const short8*)(Bsq + (j * 16 + lr) * BPITCH + qd * 8);
        if (k < 15) {
            __syncthreads();                   // all frag reads landed; LDS free
            if (USE_W2) stageA_glds((k + 1) * BK); else stageA_fp32((k + 1) * BK);
            writeB();                          // tile k+1 from breg
            if (k < 14) loadB((k + 2) * BK);
        }
        #pragma unroll
        for (int i = 0; i < 4; ++i)
            #pragma unroll
            for (int j = 0; j < 4; ++j)
                acc[i][j] = __builtin_amdgcn_mfma_f32_16x16x32_bf16(
                    afr[i], bfr[j], acc[i][j], 0, 0, 0);
    }

    // ---- epilogue: LDS transpose -> full-line float4 stores
    const int q = wave;
    const int m16s = tid >> 4;
    const int rs   = (tid >> 2) & 3;
    const int ws   = (tid & 3) * 16;
    const int rgs  = nb * 4 + rs;
    const int obb  = rgs >> 4;
    const int oh4  = rgs & 15;
    #pragma unroll
    for (int ic = 0; ic < 4; ++ic) {
        __syncthreads();                       // prior reads of smem done
        #pragma unroll
        for (int j = 0; j < 4; ++j)
            #pragma unroll
            for (int g = 0; g < 4; ++g)
                T[((qd * 4 + g) * 4 + j) * 68 + lr * 4 + q] = acc[ic][j][g];
        __syncthreads();
        float* op = out + ((size_t)obb * CT + m0 + ic * 16 + m16s) * HW
                        + (oh4 * 4 + r) * 64 + ws;
        const float* tp = T + (m16s * 4 + rs) * 68 + ws;
        #pragma unroll
        for (int c = 0; c < 4; ++c)
            ((float4*)op)[c] = ((const float4*)tp)[c];
    }
}

extern "C" void kernel_launch(void* const* d_in, const int* in_sizes, int n_in,
                              void* d_out, int out_size, void* d_ws, size_t ws_size,
                              hipStream_t stream) {
    const float* x  = (const float*)d_in[0];
    const float* Wg = (const float*)d_in[1];
    float* out = (float*)d_out;
    dim3 grid(64, 8, 4);   // nb fastest: 8 mb siblings land on same XCD (id step 64)
    if (ws_size >= (size_t)16 * 512 * 512 * 2) {
        uint16_t* W2 = (uint16_t*)d_ws;
        w2_cvt<<<2048, 256, 0, stream>>>(Wg, W2);
        gwl_main<true><<<grid, 256, 0, stream>>>(x, Wg, W2, out);
    } else {
        gwl_main<false><<<grid, 256, 0, stream>>>(x, Wg, nullptr, out);
    }
}